// Round 5
// baseline (3808.533 us; speedup 1.0000x reference)
//
#include <hip/hip_runtime.h>
#include <cstddef>

#define BB 2
#define LL 1024
#define DM 768
#define DI 1536
#define NST 16
#define DTR 48
#define DINT 1536
#define NLAYER 2
#define ML (BB*LL)      /* 2048 rows per direction */
#define NCH 32
#define CLEN (LL/NCH)   /* 32 */

typedef __attribute__((ext_vector_type(8))) short s16x8;
typedef __attribute__((ext_vector_type(4))) float f32x4;

static __device__ __forceinline__ float sigm(float x){ return 1.f/(1.f+__expf(-x)); }
static __device__ __forceinline__ float silu_(float x){ return x*sigm(x); }
static __device__ __forceinline__ float softplus_(float x){ return fmaxf(x,0.f)+log1pf(__expf(-fabsf(x))); }
static __device__ __forceinline__ unsigned short f2b(float x){
  unsigned int u = __float_as_uint(x);
  unsigned int r = (u + 0x7fffu + ((u>>16)&1u)) >> 16;
  return (unsigned short)r;
}
static __device__ __forceinline__ float b2f(unsigned short v){
  return __uint_as_float(((unsigned int)v) << 16);
}
// NOTE (R4 post-mortem): __builtin_amdgcn_global_load_lds staging REGRESSED 2x here —
// our per-wave addresses scatter 64B chunks over 16 rows; the DMA path thrashed L2
// (FETCH 319MB = zero-reuse volume) and amplified TCC writes 4x (1.29GB). Manual
// uint4 staging restored; only use global_load_lds with wave-contiguous segments.

// ---------------- embedding gather ----------------
__global__ void k_embed(const int* __restrict__ ids, const float* __restrict__ emb,
                        float* __restrict__ out){
  int idx = blockIdx.x*256 + threadIdx.x;
  if (idx >= ML*DM) return;
  int c = idx % DM; int bl = idx / DM;
  out[idx] = emb[(size_t)ids[bl]*DM + c];
}

// ---------------- c = a + b ----------------
__global__ void k_add(const float* __restrict__ a, const float* __restrict__ b,
                      float* __restrict__ c, int n){
  int idx = blockIdx.x*256 + threadIdx.x;
  if (idx >= n) return;
  c[idx] = a[idx] + b[idx];
}

// ---------------- fp32 -> bf16 convert ----------------
__global__ void k_f2b(const float* __restrict__ in, unsigned short* __restrict__ out, int n){
  int idx = blockIdx.x*256 + threadIdx.x;
  if (idx >= n) return;
  out[idx] = f2b(in[idx]);
}

// ---------------- fc1 interleave convert: out row 2i <- in row i; 2i+1 <- in row DINT+i ----------------
__global__ void k_f2b_il(const float* __restrict__ in, unsigned short* __restrict__ out){
  int idx = blockIdx.x*256 + threadIdx.x;   // over 2*DINT*DM
  if (idx >= 2*DINT*DM) return;
  int c = idx % DM; int r = idx / DM;
  int half = r / DINT, i = r % DINT;
  out[(size_t)(2*i + half)*DM + c] = f2b(in[idx]);
}

// ---------------- W_eff = dt_w @ x_proj[:48]  -> bf16 into wbig rows [0,1536) ----------------
__global__ void k_weff(const float* __restrict__ dw, const float* __restrict__ xp,
                       unsigned short* __restrict__ wbig){
  int idx = blockIdx.x*256 + threadIdx.x;  // over 1536*1536
  int j = idx % DI, i = idx / DI;
  float s = 0.f;
  #pragma unroll
  for (int k = 0; k < DTR; k++) s += dw[i*DTR + k] * xp[(size_t)k*DI + j];
  wbig[idx] = f2b(s);
}

// ---------------- wbig rows [1536,1664): x_proj[48:80] bf16, zero-pad rest ----------------
__global__ void k_wtail(const float* __restrict__ xp, unsigned short* __restrict__ wbig){
  int idx = blockIdx.x*256 + threadIdx.x;  // over 128*1536
  if (idx >= 128*DI) return;
  int j = idx % DI, r = idx / DI;
  unsigned short v = (r < 32) ? f2b(xp[(size_t)(DTR + r)*DI + j]) : (unsigned short)0;
  wbig[(size_t)(DI + r)*DI + j] = v;
}

// ---------------- layernorm (one wave per 768-row), fused pre-add + optional outputs ----------------
__global__ __launch_bounds__(256) void k_ln(const float* __restrict__ x,
    const float* __restrict__ add, const float* __restrict__ w, const float* __restrict__ bi,
    float* __restrict__ sumout, float* __restrict__ fout, unsigned short* __restrict__ bout,
    int acc, int rows){
  int wv = threadIdx.x >> 6, lane = threadIdx.x & 63;
  int row = blockIdx.x*4 + wv;
  if (row >= rows) return;
  const float* xr = x + (size_t)row*DM;
  float v[12]; float s = 0.f, sq = 0.f;
  #pragma unroll
  for (int i = 0; i < 12; i++){
    int c = lane + 64*i;
    float t = xr[c];
    if (add) t += add[(size_t)row*DM + c];
    if (sumout) sumout[(size_t)row*DM + c] = t;
    v[i] = t; s += t; sq += t*t;
  }
  #pragma unroll
  for (int o = 32; o; o >>= 1){ s += __shfl_xor(s, o, 64); sq += __shfl_xor(sq, o, 64); }
  float mean = s*(1.f/DM);
  float var  = sq*(1.f/DM) - mean*mean;
  float rstd = rsqrtf(var + 1e-5f);
  #pragma unroll
  for (int i = 0; i < 12; i++){
    int c = lane + 64*i;
    float o = (v[i]-mean)*rstd*w[c] + bi[c];
    if (fout){
      float oo = o;
      if (acc) oo += fout[(size_t)row*DM + c];
      fout[(size_t)row*DM + c] = oo;
    }
    if (bout) bout[(size_t)row*DM + c] = f2b(o);
  }
}

// ---------------- bf16 MFMA GEMM (manual uint4 staging): [M x N] = A[M,K] @ W[N,K]^T ----------------
// mode 0: Cf = acc (+ addsrc[(m & 2047)*N + n])
// mode 1: n<1536 -> dlb = bf16(softplus(acc+dtb[n])); 1536<=n<1568 -> bcout[m*32+(n-1536)] = acc
// mode 2: Cb = bf16(acc)
// mode 3: fc1+gate fused (interleaved W): even n -> Cb[m*(N/2) + n/2] = bf16(v * silu(partner))
__global__ __launch_bounds__(256) void k_mgemm(const unsigned short* __restrict__ A,
    const unsigned short* __restrict__ W, const float* __restrict__ addsrc,
    float* __restrict__ Cf, unsigned short* __restrict__ Cb, int N, int K, int mode,
    const float* __restrict__ dtb, unsigned short* __restrict__ dlb, float* __restrict__ bcout){
  __shared__ __align__(16) unsigned short As[4096], Bs[4096];
  int t = threadIdx.x;
  int m0 = blockIdx.y*128, n0 = blockIdx.x*128;
  int lane = t & 63, w = t >> 6;
  int wm = w & 1, wn = w >> 1;
  f32x4 acc[4][4] = {};
  for (int k0 = 0; k0 < K; k0 += 32){
    #pragma unroll
    for (int si = 0; si < 2; si++){
      int s = t + si*256;
      int row = ((s>>6)<<4) + (s & 15);
      int ko  = ((s>>4) & 3) << 3;
      *(uint4*)&As[s*8] = *(const uint4*)&A[(size_t)(m0+row)*K + k0 + ko];
      *(uint4*)&Bs[s*8] = *(const uint4*)&W[(size_t)(n0+row)*K + k0 + ko];
    }
    __syncthreads();
    s16x8 af[4], bf[4];
    #pragma unroll
    for (int i = 0; i < 4; i++) af[i] = *(const s16x8*)&As[((wm*4+i)*64 + lane)*8];
    #pragma unroll
    for (int j = 0; j < 4; j++) bf[j] = *(const s16x8*)&Bs[((wn*4+j)*64 + lane)*8];
    #pragma unroll
    for (int i = 0; i < 4; i++)
      #pragma unroll
      for (int j = 0; j < 4; j++)
        acc[i][j] = __builtin_amdgcn_mfma_f32_16x16x32_bf16(af[i], bf[j], acc[i][j], 0, 0, 0);
    __syncthreads();
  }
  int cl = lane & 15, qd = lane >> 4;
  #pragma unroll
  for (int i = 0; i < 4; i++){
    int mbase = m0 + (wm*4+i)*16 + qd*4;
    #pragma unroll
    for (int j = 0; j < 4; j++){
      int n = n0 + (wn*4+j)*16 + cl;
      #pragma unroll
      for (int r = 0; r < 4; r++){
        int m = mbase + r;
        float v = acc[i][j][r];
        if (mode == 0){
          if (addsrc) v += addsrc[(size_t)(m & (ML-1))*N + n];
          Cf[(size_t)m*N + n] = v;
        } else if (mode == 2){
          Cb[(size_t)m*N + n] = f2b(v);
        } else if (mode == 1){
          if (n < DI) dlb[(size_t)m*DI + n] = f2b(softplus_(v + dtb[n]));
          else if (n < DI + 32) bcout[(size_t)m*32 + (n - DI)] = v;
        } else {  // mode 3: gate fusion; partner column differs in bit0 of lane
          float vo = __shfl_xor(v, 1, 64);
          if ((n & 1) == 0) Cb[(size_t)m*(N>>1) + (n>>1)] = f2b(v * silu_(vo));
        }
      }
    }
  }
}

// ---------------- depthwise conv (K=4, causal fwd / anti-causal bwd) + silu -> bf16 ----------------
__global__ void k_conv(const float* __restrict__ xz, const float* __restrict__ w,
                       const float* __restrict__ bi, unsigned short* __restrict__ xcb){
  int idx = blockIdx.x*256 + threadIdx.x;   // over 2*ML*DI
  if (idx >= 2*ML*DI) return;
  int d = idx % DI; int r = idx / DI;
  int bl = r % ML; int dir = r / ML;
  int t = bl % LL; int b = bl / LL;
  float acc = bi[d];
  #pragma unroll
  for (int k = 0; k < 4; k++){
    int tp = dir ? (t + 3 - k) : (t - 3 + k);
    if (tp >= 0 && tp < LL)
      acc += w[d*4 + k] * xz[((size_t)(b*LL + tp))*(2*DI) + d];
  }
  xcb[idx] = f2b(silu_(acc));
}

// ---------------- scan phase 1: per-chunk summaries; one thread per (dir,b,ch,d), 16 states ----------------
__global__ __launch_bounds__(256) void k_scan1(
    const unsigned short* __restrict__ dlb, const unsigned short* __restrict__ xcb,
    const float* __restrict__ bc, const float* __restrict__ A_log,
    float* __restrict__ sA, float* __restrict__ sH){
  __shared__ float Bsh[CLEN*16];
  int blk = blockIdx.x;
  int dgrp = blk % (DI/256); int rest = blk / (DI/256);
  int ch = rest % NCH; rest /= NCH;
  int b = rest & 1; int dir = rest >> 1;
  int d = dgrp*256 + threadIdx.x;
  int t0 = dir ? (LL-1 - ch*CLEN) : ch*CLEN;
  long step = dir ? -1 : 1;
  long row0 = (long)dir*ML + b*LL + t0;
  #pragma unroll
  for (int rep = 0; rep < CLEN*16/256; rep++){
    int e = threadIdx.x + rep*256;
    int s = e >> 4, n = e & 15;
    Bsh[e] = bc[(size_t)(row0 + s*step)*32 + n];
  }
  __syncthreads();
  float ea[16];
  #pragma unroll
  for (int n = 0; n < 16; n++) ea[n] = -__expf(A_log[d*16 + n]) * 1.44269504f;
  float h[16], P[16];
  #pragma unroll
  for (int n = 0; n < 16; n++){ h[n] = 0.f; P[n] = 1.f; }
  long row = row0;
  for (int s = 0; s < CLEN; s++){
    float de = b2f(dlb[(size_t)row*DI + d]);
    float u  = b2f(xcb[(size_t)row*DI + d]);
    float duu = de*u;
    float Ba[16];
    const f32x4* Bv = (const f32x4*)&Bsh[s*16];
    *(f32x4*)&Ba[0] = Bv[0]; *(f32x4*)&Ba[4] = Bv[1];
    *(f32x4*)&Ba[8] = Bv[2]; *(f32x4*)&Ba[12] = Bv[3];
    #pragma unroll
    for (int n = 0; n < 16; n++){
      float dA = exp2f(de*ea[n]);
      h[n] = dA*h[n] + duu*Ba[n];
      P[n] *= dA;
    }
    row += step;
  }
  size_t sbase = ((((size_t)dir*BB + b)*NCH + ch)*DI + d)*16;
  #pragma unroll
  for (int n = 0; n < 16; n++){ sA[sbase+n] = P[n]; sH[sbase+n] = h[n]; }
}

// ---------------- scan phase 1b: serial prefix over chunk summaries -> h0 per chunk ----------------
__global__ __launch_bounds__(256) void k_prefix(
    const float* __restrict__ sA, const float* __restrict__ sH, float* __restrict__ h0){
  int gid = blockIdx.x*256 + threadIdx.x;  // over 2*BB*DI*16 = 98304
  int dn = gid % (DI*16);
  int db_ = gid / (DI*16);
  float h = 0.f;
  size_t base = (size_t)db_*NCH*DI*16 + dn;
  for (int ch = 0; ch < NCH; ch++){
    size_t idx = base + (size_t)ch*DI*16;
    h0[idx] = h;
    h = sH[idx] + sA[idx]*h;
  }
}

// ---------------- scan phase 2: rescan chunks from h0, full outputs; y(bf16) aliases xcb ----------------
__global__ __launch_bounds__(256) void k_scan2(
    const unsigned short* __restrict__ dlb, const unsigned short* __restrict__ xcb,
    const float* __restrict__ bc, const float* __restrict__ xz,
    const float* __restrict__ A_log, const float* __restrict__ Dp,
    const float* __restrict__ h0, unsigned short* __restrict__ y){
  __shared__ float BCs[CLEN*32];
  int blk = blockIdx.x;
  int dgrp = blk % (DI/256); int rest = blk / (DI/256);
  int ch = rest % NCH; rest /= NCH;
  int b = rest & 1; int dir = rest >> 1;
  int d = dgrp*256 + threadIdx.x;
  int t0 = dir ? (LL-1 - ch*CLEN) : ch*CLEN;
  long step = dir ? -1 : 1;
  long row0 = (long)dir*ML + b*LL + t0;
  #pragma unroll
  for (int rep = 0; rep < CLEN*32/256; rep++){
    int e = threadIdx.x + rep*256;
    int s = e >> 5, n = e & 31;
    BCs[e] = bc[(size_t)(row0 + s*step)*32 + n];
  }
  __syncthreads();
  float ea[16];
  #pragma unroll
  for (int n = 0; n < 16; n++) ea[n] = -__expf(A_log[d*16 + n]) * 1.44269504f;
  float dD = Dp[d];
  float h[16];
  size_t hbase = ((((size_t)dir*BB + b)*NCH + ch)*DI + d)*16;
  #pragma unroll
  for (int n = 0; n < 16; n++) h[n] = h0[hbase + n];
  long row = row0;
  long zoff = (long)dir*ML;
  for (int s = 0; s < CLEN; s++){
    float de = b2f(dlb[(size_t)row*DI + d]);
    float u  = b2f(xcb[(size_t)row*DI + d]);
    float z  = xz[(size_t)(row - zoff)*(2*DI) + DI + d];
    float duu = de*u;
    float Ba[16], Ca[16];
    const f32x4* Bv = (const f32x4*)&BCs[s*32];
    *(f32x4*)&Ba[0] = Bv[0]; *(f32x4*)&Ba[4] = Bv[1];
    *(f32x4*)&Ba[8] = Bv[2]; *(f32x4*)&Ba[12] = Bv[3];
    *(f32x4*)&Ca[0] = Bv[4]; *(f32x4*)&Ca[4] = Bv[5];
    *(f32x4*)&Ca[8] = Bv[6]; *(f32x4*)&Ca[12] = Bv[7];
    float p0 = 0.f, p1 = 0.f, p2 = 0.f, p3 = 0.f;
    #pragma unroll
    for (int n = 0; n < 16; n += 4){
      float dA0 = exp2f(de*ea[n]),   dA1 = exp2f(de*ea[n+1]);
      float dA2 = exp2f(de*ea[n+2]), dA3 = exp2f(de*ea[n+3]);
      h[n]   = dA0*h[n]   + duu*Ba[n];
      h[n+1] = dA1*h[n+1] + duu*Ba[n+1];
      h[n+2] = dA2*h[n+2] + duu*Ba[n+2];
      h[n+3] = dA3*h[n+3] + duu*Ba[n+3];
      p0 = fmaf(h[n],   Ca[n],   p0);
      p1 = fmaf(h[n+1], Ca[n+1], p1);
      p2 = fmaf(h[n+2], Ca[n+2], p2);
      p3 = fmaf(h[n+3], Ca[n+3], p3);
    }
    float p = (p0+p1) + (p2+p3);
    y[(size_t)row*DI + d] = f2b((p + u*dD) * silu_(z));
    row += step;
  }
}

// ---------------- mean over L ----------------
__global__ void k_mean(const float* __restrict__ x, float* __restrict__ out){
  int d = blockIdx.x*256 + threadIdx.x;
  int b = blockIdx.y;
  if (d >= DM) return;
  float s = 0.f;
  for (int t = 0; t < LL; t++) s += x[((size_t)(b*LL + t))*DM + d];
  out[b*DM + d] = s*(1.f/LL);
}

extern "C" void kernel_launch(void* const* d_in, const int* in_sizes, int n_in,
                              void* d_out, int out_size, void* d_ws, size_t ws_size,
                              hipStream_t stream){
  const int*   ids     = (const int*)d_in[0];
  const float* embed   = (const float*)d_in[1];
  const float* norm_w  = (const float*)d_in[2];
  const float* norm_b  = (const float*)d_in[3];
  const float* in_proj = (const float*)d_in[4];
  const float* conv_w  = (const float*)d_in[5];
  const float* conv_b  = (const float*)d_in[6];
  const float* x_proj  = (const float*)d_in[7];
  const float* dt_w    = (const float*)d_in[8];
  const float* dt_b    = (const float*)d_in[9];
  const float* A_log   = (const float*)d_in[10];
  const float* Dp      = (const float*)d_in[11];
  const float* out_pj  = (const float*)d_in[12];
  const float* norm2_w = (const float*)d_in[13];
  const float* norm2_b = (const float*)d_in[14];
  const float* fc1     = (const float*)d_in[15];
  const float* fc2     = (const float*)d_in[16];
  const float* normf_w = (const float*)d_in[17];
  const float* normf_b = (const float*)d_in[18];
  float* out = (float*)d_out;

  const size_t BLD   = (size_t)ML*DM;
  const size_t BLDI  = (size_t)ML*DI;
  const size_t BL2DI = (size_t)ML*2*DI;
  const size_t SUMN  = (size_t)2*BB*NCH*DI*16;   // 3,145,728

  // fp32 arena
  float* f = (float*)d_ws; size_t off = 0;
  float* h     = f+off; off += BLD;
  float* res   = f+off; off += BLD;
  float* rc    = f+off; off += BLD;
  float* resd  = f+off; off += 2*BLD;
  float* xz    = f+off; off += BL2DI;      // mlpo aliases after scan2
  float* bc    = f+off; off += (size_t)2*ML*32;
  float* sA    = f+off; off += SUMN;       // gb aliases after prefix
  float* sH    = f+off; off += SUMN;
  float* h0    = f+off; off += SUMN;
  float*          mlpo = xz;
  unsigned short* gb   = (unsigned short*)sA;   // 2*ML*DINT ushorts = SUMN*4 bytes exactly
  // bf16 arena
  unsigned short* u16 = (unsigned short*)(f + off); size_t uo = 0;
  unsigned short* xlnb = u16+uo; uo += BLD;
  unsigned short* x2b  = u16+uo; uo += 2*BLD;
  unsigned short* xcb  = u16+uo; uo += 2*BLDI;   // y aliases
  unsigned short* dlb  = u16+uo; uo += 2*BLDI;
  unsigned short* wib  = u16+uo; uo += (size_t)2*DI*DM;   // wf1i aliases
  unsigned short* wob  = u16+uo; uo += (size_t)DM*DI;     // wf2b aliases
  unsigned short* wbig = u16+uo; uo += (size_t)1664*DI;
  unsigned short* yb   = xcb;
  unsigned short* wf1i = wib;
  unsigned short* wf2b = wob;
  (void)ws_size; (void)in_sizes; (void)n_in; (void)out_size;

  dim3 blk(256);
  auto cdiv = [](int a, int b){ return (a + b - 1)/b; };
  const int scan_blocks = 2*2*NCH*(DI/256);   // 768

  k_embed<<<cdiv(ML*DM,256), blk, 0, stream>>>(ids, embed, h);

  for (int l = 0; l < NLAYER; l++){
    const float* nw  = norm_w  + l*DM;
    const float* nb  = norm_b  + l*DM;
    const float* ip  = in_proj + (size_t)l*2*DI*DM;
    const float* cw  = conv_w  + (size_t)l*DI*4;
    const float* cb  = conv_b  + (size_t)l*DI;
    const float* xp  = x_proj  + (size_t)l*(DTR+2*NST)*DI;
    const float* dw  = dt_w    + (size_t)l*DI*DTR;
    const float* db  = dt_b    + (size_t)l*DI;
    const float* al  = A_log   + (size_t)l*DI*NST;
    const float* dpl = Dp      + (size_t)l*DI;
    const float* op  = out_pj  + (size_t)l*DM*DI;
    const float* n2w = norm2_w + l*DM;
    const float* n2b = norm2_b + l*DM;
    const float* f1  = fc1 + (size_t)l*2*DINT*DM;
    const float* f2  = fc2 + (size_t)l*DM*DINT;

    // weight prep
    k_f2b<<<cdiv(2*DI*DM,256), blk, 0, stream>>>(ip, wib, 2*DI*DM);
    k_f2b<<<cdiv(DM*DI,256), blk, 0, stream>>>(op, wob, DM*DI);
    k_weff<<<cdiv(DI*DI,256), blk, 0, stream>>>(dw, xp, wbig);
    k_wtail<<<cdiv(128*DI,256), blk, 0, stream>>>(xp, wbig);

    // rc = h (+ res); xlnb = bf16(LN(rc))
    k_ln<<<ML/4, blk, 0, stream>>>(h, (l==0)?nullptr:res, nw, nb, rc, nullptr, xlnb, 0, ML);
    // xz = xln @ in_proj^T
    k_mgemm<<<dim3(2*DI/128, ML/128), blk, 0, stream>>>(xlnb, wib, nullptr, xz, nullptr, 2*DI, DM, 0, nullptr, nullptr, nullptr);
    // conv both dirs -> xcb bf16
    k_conv<<<cdiv(2*ML*DI,256), blk, 0, stream>>>(xz, cw, cb, xcb);
    // fused [delta | B C | pad] GEMM, both dirs (M=4096)
    k_mgemm<<<dim3(1664/128, 2*ML/128), blk, 0, stream>>>(xcb, wbig, nullptr, nullptr, nullptr, 1664, DI, 1, db, dlb, bc);
    // chunked scan: summaries -> prefix -> rescan
    k_scan1<<<scan_blocks, blk, 0, stream>>>(dlb, xcb, bc, al, sA, sH);
    k_prefix<<<(2*BB*DI*16)/256, blk, 0, stream>>>(sA, sH, h0);
    k_scan2<<<scan_blocks, blk, 0, stream>>>(dlb, xcb, bc, xz, al, dpl, h0, yb);
    // fc1 weights (interleaved) into wib region (in_proj GEMM done)
    k_f2b_il<<<cdiv(2*DINT*DM,256), blk, 0, stream>>>(f1, wf1i);
    // resd = y @ out_proj^T + rc
    k_mgemm<<<dim3(DM/128, 2*ML/128), blk, 0, stream>>>(yb, wob, rc, resd, nullptr, DM, DI, 0, nullptr, nullptr, nullptr);
    // fc2 weights into wob region
    k_f2b<<<cdiv(DM*DINT,256), blk, 0, stream>>>(f2, wf2b, DM*DINT);
    // LN2 both dirs -> x2b
    k_ln<<<2*ML/4, blk, 0, stream>>>(resd, nullptr, n2w, n2b, nullptr, nullptr, x2b, 0, 2*ML);
    // fc1 + gate fused (mode 3) -> gb bf16
    k_mgemm<<<dim3(2*DINT/128, 2*ML/128), blk, 0, stream>>>(x2b, wf1i, nullptr, nullptr, gb, 2*DINT, DM, 3, nullptr, nullptr, nullptr);
    // fc2 -> mlpo fp32 (aliases xz)
    k_mgemm<<<dim3(DM/128, 2*ML/128), blk, 0, stream>>>(gb, wf2b, nullptr, mlpo, nullptr, DM, DINT, 0, nullptr, nullptr, nullptr);
    // h = LN_f(mlpo_f) + LN_f(mlpo_b)
    k_ln<<<ML/4, blk, 0, stream>>>(mlpo, nullptr, normf_w, normf_b, nullptr, h, nullptr, 0, ML);
    k_ln<<<ML/4, blk, 0, stream>>>(mlpo + BLD, nullptr, normf_w, normf_b, nullptr, h, nullptr, 1, ML);
    // res = resd0 + resd1
    k_add<<<cdiv(ML*DM,256), blk, 0, stream>>>(resd, resd + BLD, res, ML*DM);
  }

  // final: LN(h + res) -> rc; mean over L
  k_ln<<<ML/4, blk, 0, stream>>>(h, res, normf_w, normf_b, nullptr, rc, nullptr, 0, ML);
  k_mean<<<dim3(3, BB), blk, 0, stream>>>(rc, out);
}

// Round 6
// 1285.502 us; speedup vs baseline: 2.9627x; 2.9627x over previous
//
#include <hip/hip_runtime.h>
#include <cstddef>

#define BB 2
#define LL 1024
#define DM 768
#define DI 1536
#define NST 16
#define DTR 48
#define DINT 1536
#define NLAYER 2
#define ML (BB*LL)      /* 2048 rows per direction */
#define NCH 32
#define CLEN (LL/NCH)   /* 32 */

typedef __attribute__((ext_vector_type(8))) short s16x8;
typedef __attribute__((ext_vector_type(4))) float f32x4;

static __device__ __forceinline__ float sigm(float x){ return 1.f/(1.f+__expf(-x)); }
static __device__ __forceinline__ float silu_(float x){ return x*sigm(x); }
static __device__ __forceinline__ float softplus_(float x){ return fmaxf(x,0.f)+log1pf(__expf(-fabsf(x))); }
static __device__ __forceinline__ unsigned short f2b(float x){
  unsigned int u = __float_as_uint(x);
  unsigned int r = (u + 0x7fffu + ((u>>16)&1u)) >> 16;
  return (unsigned short)r;
}
static __device__ __forceinline__ float b2f(unsigned short v){
  return __uint_as_float(((unsigned int)v) << 16);
}
// R5 post-mortem: global_load_lds revert changed NOTHING (R4==R5) -> R4's regression
// came from the fc1 gate-fusion (mode-3 unified kernel) or scan restructure. This round:
// GEMMs reverted to R3 semantics as three single-purpose kernels; new scans kept.

// ---------------- embedding gather ----------------
__global__ void k_embed(const int* __restrict__ ids, const float* __restrict__ emb,
                        float* __restrict__ out){
  int idx = blockIdx.x*256 + threadIdx.x;
  if (idx >= ML*DM) return;
  int c = idx % DM; int bl = idx / DM;
  out[idx] = emb[(size_t)ids[bl]*DM + c];
}

// ---------------- c = a + b ----------------
__global__ void k_add(const float* __restrict__ a, const float* __restrict__ b,
                      float* __restrict__ c, int n){
  int idx = blockIdx.x*256 + threadIdx.x;
  if (idx >= n) return;
  c[idx] = a[idx] + b[idx];
}

// ---------------- fp32 -> bf16 convert ----------------
__global__ void k_f2b(const float* __restrict__ in, unsigned short* __restrict__ out, int n){
  int idx = blockIdx.x*256 + threadIdx.x;
  if (idx >= n) return;
  out[idx] = f2b(in[idx]);
}

// ---------------- W_eff = dt_w @ x_proj[:48]  -> bf16 into wbig rows [0,1536) ----------------
__global__ void k_weff(const float* __restrict__ dw, const float* __restrict__ xp,
                       unsigned short* __restrict__ wbig){
  int idx = blockIdx.x*256 + threadIdx.x;  // over 1536*1536
  int j = idx % DI, i = idx / DI;
  float s = 0.f;
  #pragma unroll
  for (int k = 0; k < DTR; k++) s += dw[i*DTR + k] * xp[(size_t)k*DI + j];
  wbig[idx] = f2b(s);
}

// ---------------- wbig rows [1536,1664): x_proj[48:80] bf16, zero-pad rest ----------------
__global__ void k_wtail(const float* __restrict__ xp, unsigned short* __restrict__ wbig){
  int idx = blockIdx.x*256 + threadIdx.x;  // over 128*1536
  if (idx >= 128*DI) return;
  int j = idx % DI, r = idx / DI;
  unsigned short v = (r < 32) ? f2b(xp[(size_t)(DTR + r)*DI + j]) : (unsigned short)0;
  wbig[(size_t)(DI + r)*DI + j] = v;
}

// ---------------- layernorm (one wave per 768-row), fused pre-add + optional outputs ----------------
__global__ __launch_bounds__(256) void k_ln(const float* __restrict__ x,
    const float* __restrict__ add, const float* __restrict__ w, const float* __restrict__ bi,
    float* __restrict__ sumout, float* __restrict__ fout, unsigned short* __restrict__ bout,
    int acc, int rows){
  int wv = threadIdx.x >> 6, lane = threadIdx.x & 63;
  int row = blockIdx.x*4 + wv;
  if (row >= rows) return;
  const float* xr = x + (size_t)row*DM;
  float v[12]; float s = 0.f, sq = 0.f;
  #pragma unroll
  for (int i = 0; i < 12; i++){
    int c = lane + 64*i;
    float t = xr[c];
    if (add) t += add[(size_t)row*DM + c];
    if (sumout) sumout[(size_t)row*DM + c] = t;
    v[i] = t; s += t; sq += t*t;
  }
  #pragma unroll
  for (int o = 32; o; o >>= 1){ s += __shfl_xor(s, o, 64); sq += __shfl_xor(sq, o, 64); }
  float mean = s*(1.f/DM);
  float var  = sq*(1.f/DM) - mean*mean;
  float rstd = rsqrtf(var + 1e-5f);
  #pragma unroll
  for (int i = 0; i < 12; i++){
    int c = lane + 64*i;
    float o = (v[i]-mean)*rstd*w[c] + bi[c];
    if (fout){
      float oo = o;
      if (acc) oo += fout[(size_t)row*DM + c];
      fout[(size_t)row*DM + c] = oo;
    }
    if (bout) bout[(size_t)row*DM + c] = f2b(o);
  }
}

// ---------------- shared MFMA GEMM core: 128x128 tile, BK=32, manual uint4 staging ----------------
static __device__ __forceinline__ void mgemm_core(
    const unsigned short* __restrict__ A, const unsigned short* __restrict__ W, int K,
    unsigned short* As, unsigned short* Bs, f32x4 (&acc)[4][4]){
  int t = threadIdx.x;
  int m0 = blockIdx.y*128, n0 = blockIdx.x*128;
  int lane = t & 63, w = t >> 6;
  int wm = w & 1, wn = w >> 1;
  for (int k0 = 0; k0 < K; k0 += 32){
    #pragma unroll
    for (int si = 0; si < 2; si++){
      int s = t + si*256;
      int row = ((s>>6)<<4) + (s & 15);
      int ko  = ((s>>4) & 3) << 3;
      *(uint4*)&As[s*8] = *(const uint4*)&A[(size_t)(m0+row)*K + k0 + ko];
      *(uint4*)&Bs[s*8] = *(const uint4*)&W[(size_t)(n0+row)*K + k0 + ko];
    }
    __syncthreads();
    s16x8 af[4], bf[4];
    #pragma unroll
    for (int i = 0; i < 4; i++) af[i] = *(const s16x8*)&As[((wm*4+i)*64 + lane)*8];
    #pragma unroll
    for (int j = 0; j < 4; j++) bf[j] = *(const s16x8*)&Bs[((wn*4+j)*64 + lane)*8];
    #pragma unroll
    for (int i = 0; i < 4; i++)
      #pragma unroll
      for (int j = 0; j < 4; j++)
        acc[i][j] = __builtin_amdgcn_mfma_f32_16x16x32_bf16(af[i], bf[j], acc[i][j], 0, 0, 0);
    __syncthreads();
  }
}

// mode 0: Cf = acc (+ addsrc[(m & 2047)*N + n])
__global__ __launch_bounds__(256) void k_mgemm0(const unsigned short* __restrict__ A,
    const unsigned short* __restrict__ W, const float* __restrict__ addsrc,
    float* __restrict__ Cf, int N, int K){
  __shared__ __align__(16) unsigned short As[4096], Bs[4096];
  f32x4 acc[4][4] = {};
  mgemm_core(A, W, K, As, Bs, acc);
  int t = threadIdx.x, lane = t & 63, w = t >> 6;
  int wm = w & 1, wn = w >> 1;
  int m0 = blockIdx.y*128, n0 = blockIdx.x*128;
  int cl = lane & 15, qd = lane >> 4;
  #pragma unroll
  for (int i = 0; i < 4; i++){
    int mbase = m0 + (wm*4+i)*16 + qd*4;
    #pragma unroll
    for (int j = 0; j < 4; j++){
      int n = n0 + (wn*4+j)*16 + cl;
      #pragma unroll
      for (int r = 0; r < 4; r++){
        int m = mbase + r;
        float v = acc[i][j][r];
        if (addsrc) v += addsrc[(size_t)(m & (ML-1))*N + n];
        Cf[(size_t)m*N + n] = v;
      }
    }
  }
}

// mode 1 (dbc): n<1536 -> dlb = bf16(softplus(acc+dtb[n])); 1536<=n<1568 -> bcout[m*32+(n-1536)]
__global__ __launch_bounds__(256) void k_mgemm1(const unsigned short* __restrict__ A,
    const unsigned short* __restrict__ W, const float* __restrict__ dtb,
    unsigned short* __restrict__ dlb, float* __restrict__ bcout, int K){
  __shared__ __align__(16) unsigned short As[4096], Bs[4096];
  f32x4 acc[4][4] = {};
  mgemm_core(A, W, K, As, Bs, acc);
  int t = threadIdx.x, lane = t & 63, w = t >> 6;
  int wm = w & 1, wn = w >> 1;
  int m0 = blockIdx.y*128, n0 = blockIdx.x*128;
  int cl = lane & 15, qd = lane >> 4;
  #pragma unroll
  for (int i = 0; i < 4; i++){
    int mbase = m0 + (wm*4+i)*16 + qd*4;
    #pragma unroll
    for (int j = 0; j < 4; j++){
      int n = n0 + (wn*4+j)*16 + cl;
      #pragma unroll
      for (int r = 0; r < 4; r++){
        int m = mbase + r;
        float v = acc[i][j][r];
        if (n < DI) dlb[(size_t)m*DI + n] = f2b(softplus_(v + dtb[n]));
        else if (n < DI + 32) bcout[(size_t)m*32 + (n - DI)] = v;
      }
    }
  }
}

// mode 2: Cb = bf16(acc)
__global__ __launch_bounds__(256) void k_mgemm2(const unsigned short* __restrict__ A,
    const unsigned short* __restrict__ W, unsigned short* __restrict__ Cb, int N, int K){
  __shared__ __align__(16) unsigned short As[4096], Bs[4096];
  f32x4 acc[4][4] = {};
  mgemm_core(A, W, K, As, Bs, acc);
  int t = threadIdx.x, lane = t & 63, w = t >> 6;
  int wm = w & 1, wn = w >> 1;
  int m0 = blockIdx.y*128, n0 = blockIdx.x*128;
  int cl = lane & 15, qd = lane >> 4;
  #pragma unroll
  for (int i = 0; i < 4; i++){
    int mbase = m0 + (wm*4+i)*16 + qd*4;
    #pragma unroll
    for (int j = 0; j < 4; j++){
      int n = n0 + (wn*4+j)*16 + cl;
      #pragma unroll
      for (int r = 0; r < 4; r++){
        int m = mbase + r;
        Cb[(size_t)m*N + n] = f2b(acc[i][j][r]);
      }
    }
  }
}

// ---------------- depthwise conv (K=4, causal fwd / anti-causal bwd) + silu -> bf16 ----------------
__global__ void k_conv(const float* __restrict__ xz, const float* __restrict__ w,
                       const float* __restrict__ bi, unsigned short* __restrict__ xcb){
  int idx = blockIdx.x*256 + threadIdx.x;   // over 2*ML*DI
  if (idx >= 2*ML*DI) return;
  int d = idx % DI; int r = idx / DI;
  int bl = r % ML; int dir = r / ML;
  int t = bl % LL; int b = bl / LL;
  float acc = bi[d];
  #pragma unroll
  for (int k = 0; k < 4; k++){
    int tp = dir ? (t + 3 - k) : (t - 3 + k);
    if (tp >= 0 && tp < LL)
      acc += w[d*4 + k] * xz[((size_t)(b*LL + tp))*(2*DI) + d];
  }
  xcb[idx] = f2b(silu_(acc));
}

// ---------------- scan phase 1: per-chunk summaries; one thread per (dir,b,ch,d), 16 states ----------------
__global__ __launch_bounds__(256) void k_scan1(
    const unsigned short* __restrict__ dlb, const unsigned short* __restrict__ xcb,
    const float* __restrict__ bc, const float* __restrict__ A_log,
    float* __restrict__ sA, float* __restrict__ sH){
  __shared__ float Bsh[CLEN*16];
  int blk = blockIdx.x;
  int dgrp = blk % (DI/256); int rest = blk / (DI/256);
  int ch = rest % NCH; rest /= NCH;
  int b = rest & 1; int dir = rest >> 1;
  int d = dgrp*256 + threadIdx.x;
  int t0 = dir ? (LL-1 - ch*CLEN) : ch*CLEN;
  long step = dir ? -1 : 1;
  long row0 = (long)dir*ML + b*LL + t0;
  #pragma unroll
  for (int rep = 0; rep < CLEN*16/256; rep++){
    int e = threadIdx.x + rep*256;
    int s = e >> 4, n = e & 15;
    Bsh[e] = bc[(size_t)(row0 + s*step)*32 + n];
  }
  __syncthreads();
  float ea[16];
  #pragma unroll
  for (int n = 0; n < 16; n++) ea[n] = -__expf(A_log[d*16 + n]) * 1.44269504f;
  float h[16], P[16];
  #pragma unroll
  for (int n = 0; n < 16; n++){ h[n] = 0.f; P[n] = 1.f; }
  long row = row0;
  for (int s = 0; s < CLEN; s++){
    float de = b2f(dlb[(size_t)row*DI + d]);
    float u  = b2f(xcb[(size_t)row*DI + d]);
    float duu = de*u;
    float Ba[16];
    const f32x4* Bv = (const f32x4*)&Bsh[s*16];
    *(f32x4*)&Ba[0] = Bv[0]; *(f32x4*)&Ba[4] = Bv[1];
    *(f32x4*)&Ba[8] = Bv[2]; *(f32x4*)&Ba[12] = Bv[3];
    #pragma unroll
    for (int n = 0; n < 16; n++){
      float dA = exp2f(de*ea[n]);
      h[n] = dA*h[n] + duu*Ba[n];
      P[n] *= dA;
    }
    row += step;
  }
  size_t sbase = ((((size_t)dir*BB + b)*NCH + ch)*DI + d)*16;
  #pragma unroll
  for (int n = 0; n < 16; n++){ sA[sbase+n] = P[n]; sH[sbase+n] = h[n]; }
}

// ---------------- scan phase 1b: serial prefix over chunk summaries -> h0 per chunk ----------------
__global__ __launch_bounds__(256) void k_prefix(
    const float* __restrict__ sA, const float* __restrict__ sH, float* __restrict__ h0){
  int gid = blockIdx.x*256 + threadIdx.x;  // over 2*BB*DI*16 = 98304
  int dn = gid % (DI*16);
  int db_ = gid / (DI*16);
  float h = 0.f;
  size_t base = (size_t)db_*NCH*DI*16 + dn;
  for (int ch = 0; ch < NCH; ch++){
    size_t idx = base + (size_t)ch*DI*16;
    h0[idx] = h;
    h = sH[idx] + sA[idx]*h;
  }
}

// ---------------- scan phase 2: rescan chunks from h0, full outputs; y(bf16) aliases xcb ----------------
__global__ __launch_bounds__(256) void k_scan2(
    const unsigned short* __restrict__ dlb, const unsigned short* __restrict__ xcb,
    const float* __restrict__ bc, const float* __restrict__ xz,
    const float* __restrict__ A_log, const float* __restrict__ Dp,
    const float* __restrict__ h0, unsigned short* __restrict__ y){
  __shared__ float BCs[CLEN*32];
  int blk = blockIdx.x;
  int dgrp = blk % (DI/256); int rest = blk / (DI/256);
  int ch = rest % NCH; rest /= NCH;
  int b = rest & 1; int dir = rest >> 1;
  int d = dgrp*256 + threadIdx.x;
  int t0 = dir ? (LL-1 - ch*CLEN) : ch*CLEN;
  long step = dir ? -1 : 1;
  long row0 = (long)dir*ML + b*LL + t0;
  #pragma unroll
  for (int rep = 0; rep < CLEN*32/256; rep++){
    int e = threadIdx.x + rep*256;
    int s = e >> 5, n = e & 31;
    BCs[e] = bc[(size_t)(row0 + s*step)*32 + n];
  }
  __syncthreads();
  float ea[16];
  #pragma unroll
  for (int n = 0; n < 16; n++) ea[n] = -__expf(A_log[d*16 + n]) * 1.44269504f;
  float dD = Dp[d];
  float h[16];
  size_t hbase = ((((size_t)dir*BB + b)*NCH + ch)*DI + d)*16;
  #pragma unroll
  for (int n = 0; n < 16; n++) h[n] = h0[hbase + n];
  long row = row0;
  long zoff = (long)dir*ML;
  for (int s = 0; s < CLEN; s++){
    float de = b2f(dlb[(size_t)row*DI + d]);
    float u  = b2f(xcb[(size_t)row*DI + d]);
    float z  = xz[(size_t)(row - zoff)*(2*DI) + DI + d];
    float duu = de*u;
    float Ba[16], Ca[16];
    const f32x4* Bv = (const f32x4*)&BCs[s*32];
    *(f32x4*)&Ba[0] = Bv[0]; *(f32x4*)&Ba[4] = Bv[1];
    *(f32x4*)&Ba[8] = Bv[2]; *(f32x4*)&Ba[12] = Bv[3];
    *(f32x4*)&Ca[0] = Bv[4]; *(f32x4*)&Ca[4] = Bv[5];
    *(f32x4*)&Ca[8] = Bv[6]; *(f32x4*)&Ca[12] = Bv[7];
    float p0 = 0.f, p1 = 0.f, p2 = 0.f, p3 = 0.f;
    #pragma unroll
    for (int n = 0; n < 16; n += 4){
      float dA0 = exp2f(de*ea[n]),   dA1 = exp2f(de*ea[n+1]);
      float dA2 = exp2f(de*ea[n+2]), dA3 = exp2f(de*ea[n+3]);
      h[n]   = dA0*h[n]   + duu*Ba[n];
      h[n+1] = dA1*h[n+1] + duu*Ba[n+1];
      h[n+2] = dA2*h[n+2] + duu*Ba[n+2];
      h[n+3] = dA3*h[n+3] + duu*Ba[n+3];
      p0 = fmaf(h[n],   Ca[n],   p0);
      p1 = fmaf(h[n+1], Ca[n+1], p1);
      p2 = fmaf(h[n+2], Ca[n+2], p2);
      p3 = fmaf(h[n+3], Ca[n+3], p3);
    }
    float p = (p0+p1) + (p2+p3);
    y[(size_t)row*DI + d] = f2b((p + u*dD) * silu_(z));
    row += step;
  }
}

// ---------------- MLP gating: g = a * silu(gate), bf16 in/out ----------------
__global__ void k_gate(const unsigned short* __restrict__ fc1o, unsigned short* __restrict__ g){
  int idx = blockIdx.x*256 + threadIdx.x;   // over 2*ML*DINT
  if (idx >= 2*ML*DINT) return;
  int i = idx % DINT; int bl = idx / DINT;
  float aa = b2f(fc1o[(size_t)bl*2*DINT + i]);
  float gt = b2f(fc1o[(size_t)bl*2*DINT + DINT + i]);
  g[idx] = f2b(aa * silu_(gt));
}

// ---------------- mean over L ----------------
__global__ void k_mean(const float* __restrict__ x, float* __restrict__ out){
  int d = blockIdx.x*256 + threadIdx.x;
  int b = blockIdx.y;
  if (d >= DM) return;
  float s = 0.f;
  for (int t = 0; t < LL; t++) s += x[((size_t)(b*LL + t))*DM + d];
  out[b*DM + d] = s*(1.f/LL);
}

extern "C" void kernel_launch(void* const* d_in, const int* in_sizes, int n_in,
                              void* d_out, int out_size, void* d_ws, size_t ws_size,
                              hipStream_t stream){
  const int*   ids     = (const int*)d_in[0];
  const float* embed   = (const float*)d_in[1];
  const float* norm_w  = (const float*)d_in[2];
  const float* norm_b  = (const float*)d_in[3];
  const float* in_proj = (const float*)d_in[4];
  const float* conv_w  = (const float*)d_in[5];
  const float* conv_b  = (const float*)d_in[6];
  const float* x_proj  = (const float*)d_in[7];
  const float* dt_w    = (const float*)d_in[8];
  const float* dt_b    = (const float*)d_in[9];
  const float* A_log   = (const float*)d_in[10];
  const float* Dp      = (const float*)d_in[11];
  const float* out_pj  = (const float*)d_in[12];
  const float* norm2_w = (const float*)d_in[13];
  const float* norm2_b = (const float*)d_in[14];
  const float* fc1     = (const float*)d_in[15];
  const float* fc2     = (const float*)d_in[16];
  const float* normf_w = (const float*)d_in[17];
  const float* normf_b = (const float*)d_in[18];
  float* out = (float*)d_out;

  const size_t BLD   = (size_t)ML*DM;
  const size_t BLDI  = (size_t)ML*DI;
  const size_t BL2DI = (size_t)ML*2*DI;
  const size_t SUMN  = (size_t)2*BB*NCH*DI*16;   // 3,145,728

  // fp32 arena
  float* f = (float*)d_ws; size_t off = 0;
  float* h     = f+off; off += BLD;
  float* res   = f+off; off += BLD;
  float* rc    = f+off; off += BLD;
  float* resd  = f+off; off += 2*BLD;
  float* xz    = f+off; off += BL2DI;      // mlpo aliases after scan2
  float* bc    = f+off; off += (size_t)2*ML*32;
  float* sA    = f+off; off += SUMN;       // gb aliases after prefix
  float* sH    = f+off; off += SUMN;
  float* h0    = f+off; off += SUMN;
  float*          mlpo = xz;
  unsigned short* gb   = (unsigned short*)sA;   // 2*ML*DINT ushorts = 12.6 MB, fits in sA
  // bf16 arena
  unsigned short* u16 = (unsigned short*)(f + off); size_t uo = 0;
  unsigned short* xlnb = u16+uo; uo += BLD;
  unsigned short* x2b  = u16+uo; uo += 2*BLD;
  unsigned short* xcb  = u16+uo; uo += 2*BLDI;   // y aliases; fc1o spans xcb+dlb
  unsigned short* dlb  = u16+uo; uo += 2*BLDI;
  unsigned short* wib  = u16+uo; uo += (size_t)2*DI*DM;   // wf1b aliases
  unsigned short* wob  = u16+uo; uo += (size_t)DM*DI;     // wf2b aliases
  unsigned short* wbig = u16+uo; uo += (size_t)1664*DI;
  unsigned short* yb   = xcb;
  unsigned short* fc1o = xcb;     // 2*ML x 2*DINT bf16 = xcb+dlb regions (both dead by then)
  unsigned short* wf1b = wib;
  unsigned short* wf2b = wob;
  (void)ws_size; (void)in_sizes; (void)n_in; (void)out_size;

  dim3 blk(256);
  auto cdiv = [](int a, int b){ return (a + b - 1)/b; };
  const int scan_blocks = 2*2*NCH*(DI/256);   // 768

  k_embed<<<cdiv(ML*DM,256), blk, 0, stream>>>(ids, embed, h);

  for (int l = 0; l < NLAYER; l++){
    const float* nw  = norm_w  + l*DM;
    const float* nb  = norm_b  + l*DM;
    const float* ip  = in_proj + (size_t)l*2*DI*DM;
    const float* cw  = conv_w  + (size_t)l*DI*4;
    const float* cb  = conv_b  + (size_t)l*DI;
    const float* xp  = x_proj  + (size_t)l*(DTR+2*NST)*DI;
    const float* dw  = dt_w    + (size_t)l*DI*DTR;
    const float* db  = dt_b    + (size_t)l*DI;
    const float* al  = A_log   + (size_t)l*DI*NST;
    const float* dpl = Dp      + (size_t)l*DI;
    const float* op  = out_pj  + (size_t)l*DM*DI;
    const float* n2w = norm2_w + l*DM;
    const float* n2b = norm2_b + l*DM;
    const float* f1  = fc1 + (size_t)l*2*DINT*DM;
    const float* f2  = fc2 + (size_t)l*DM*DINT;

    // weight prep
    k_f2b<<<cdiv(2*DI*DM,256), blk, 0, stream>>>(ip, wib, 2*DI*DM);
    k_f2b<<<cdiv(DM*DI,256), blk, 0, stream>>>(op, wob, DM*DI);
    k_weff<<<cdiv(DI*DI,256), blk, 0, stream>>>(dw, xp, wbig);
    k_wtail<<<cdiv(128*DI,256), blk, 0, stream>>>(xp, wbig);

    // rc = h (+ res); xlnb = bf16(LN(rc))
    k_ln<<<ML/4, blk, 0, stream>>>(h, (l==0)?nullptr:res, nw, nb, rc, nullptr, xlnb, 0, ML);
    // xz = xln @ in_proj^T
    k_mgemm0<<<dim3(2*DI/128, ML/128), blk, 0, stream>>>(xlnb, wib, nullptr, xz, 2*DI, DM);
    // conv both dirs -> xcb bf16
    k_conv<<<cdiv(2*ML*DI,256), blk, 0, stream>>>(xz, cw, cb, xcb);
    // fused [delta | B C | pad] GEMM, both dirs (M=4096)
    k_mgemm1<<<dim3(1664/128, 2*ML/128), blk, 0, stream>>>(xcb, wbig, db, dlb, bc, DI);
    // chunked scan: summaries -> prefix -> rescan
    k_scan1<<<scan_blocks, blk, 0, stream>>>(dlb, xcb, bc, al, sA, sH);
    k_prefix<<<(2*BB*DI*16)/256, blk, 0, stream>>>(sA, sH, h0);
    k_scan2<<<scan_blocks, blk, 0, stream>>>(dlb, xcb, bc, xz, al, dpl, h0, yb);
    // fc1 weights into wib region (in_proj GEMM done)
    k_f2b<<<cdiv(2*DINT*DM,256), blk, 0, stream>>>(f1, wf1b, 2*DINT*DM);
    // resd = y @ out_proj^T + rc
    k_mgemm0<<<dim3(DM/128, 2*ML/128), blk, 0, stream>>>(yb, wob, rc, resd, DM, DI);
    // fc2 weights into wob region
    k_f2b<<<cdiv(DM*DINT,256), blk, 0, stream>>>(f2, wf2b, DM*DINT);
    // LN2 both dirs -> x2b
    k_ln<<<2*ML/4, blk, 0, stream>>>(resd, nullptr, n2w, n2b, nullptr, nullptr, x2b, 0, 2*ML);
    // fc1 -> bf16 fc1o (aliases xcb+dlb, both dead now)
    k_mgemm2<<<dim3(2*DINT/128, 2*ML/128), blk, 0, stream>>>(x2b, wf1b, fc1o, 2*DINT, DM);
    // gate -> gb (aliases sA)
    k_gate<<<cdiv(2*ML*DINT,256), blk, 0, stream>>>(fc1o, gb);
    // fc2 -> mlpo fp32 (aliases xz)
    k_mgemm0<<<dim3(DM/128, 2*ML/128), blk, 0, stream>>>(gb, wf2b, nullptr, mlpo, DM, DINT);
    // h = LN_f(mlpo_f) + LN_f(mlpo_b)
    k_ln<<<ML/4, blk, 0, stream>>>(mlpo, nullptr, normf_w, normf_b, nullptr, h, nullptr, 0, ML);
    k_ln<<<ML/4, blk, 0, stream>>>(mlpo + BLD, nullptr, normf_w, normf_b, nullptr, h, nullptr, 1, ML);
    // res = resd0 + resd1
    k_add<<<cdiv(ML*DM,256), blk, 0, stream>>>(resd, resd + BLD, res, ML*DM);
  }

  // final: LN(h + res) -> rc; mean over L
  k_ln<<<ML/4, blk, 0, stream>>>(h, res, normf_w, normf_b, nullptr, rc, nullptr, 0, ML);
  k_mean<<<dim3(3, BB), blk, 0, stream>>>(rc, out);
}

// Round 7
// 1231.270 us; speedup vs baseline: 3.0932x; 1.0440x over previous
//
#include <hip/hip_runtime.h>
#include <cstddef>

#define BB 2
#define LL 1024
#define DM 768
#define DI 1536
#define NST 16
#define DTR 48
#define DINT 1536
#define NLAYER 2
#define ML (BB*LL)      /* 2048 rows per direction */
#define NCH 32
#define CLEN (LL/NCH)   /* 32 */

typedef __attribute__((ext_vector_type(8))) short s16x8;
typedef __attribute__((ext_vector_type(4))) float f32x4;

static __device__ __forceinline__ float sigm(float x){ return 1.f/(1.f+__expf(-x)); }
static __device__ __forceinline__ float silu_(float x){ return x*sigm(x); }
static __device__ __forceinline__ float softplus_(float x){ return fmaxf(x,0.f)+log1pf(__expf(-fabsf(x))); }
static __device__ __forceinline__ unsigned short f2b(float x){
  unsigned int u = __float_as_uint(x);
  unsigned int r = (u + 0x7fffu + ((u>>16)&1u)) >> 16;
  return (unsigned short)r;
}
static __device__ __forceinline__ float b2f(unsigned short v){
  return __uint_as_float(((unsigned int)v) << 16);
}
// Journal: R4 regression = branchy unified GEMM epilogue (NOT global_load_lds, NOT scan).
// R6: single-purpose GEMMs -> 1286us; GEMMs grid-starved at 128x128 (416 blk, occ 15%).
// R7: 128x64 tiles (2x grid), weight prep hoisted+merged, xz bf16, fused tail LN.

__global__ void k_embed(const int* __restrict__ ids, const float* __restrict__ emb,
                        float* __restrict__ out){
  int idx = blockIdx.x*256 + threadIdx.x;
  if (idx >= ML*DM) return;
  int c = idx % DM; int bl = idx / DM;
  out[idx] = emb[(size_t)ids[bl]*DM + c];
}

struct Seg8 { const float* src[8]; unsigned short* dst[8]; int cum[9]; };
__global__ void k_f2bseg(Seg8 p){
  int idx = blockIdx.x*256 + threadIdx.x;
  if (idx >= p.cum[8]) return;
  int s = 0;
  #pragma unroll
  for (int i = 1; i < 8; i++) s += (idx >= p.cum[i]);
  int local = idx - p.cum[s];
  p.dst[s][local] = f2b(p.src[s][local]);
}

// wbig for ONE layer: rows<1536 = dt_w @ x_proj[:48]; rows 1536..1663 = x_proj[48:80]/pad
__global__ void k_wbig(const float* __restrict__ dw, const float* __restrict__ xp,
                       unsigned short* __restrict__ wb){
  int idx = blockIdx.x*256 + threadIdx.x;   // over 1664*DI
  if (idx >= 1664*DI) return;
  int j = idx % DI, i = idx / DI;
  unsigned short v;
  if (i < DI){
    float s = 0.f;
    #pragma unroll
    for (int k = 0; k < DTR; k++) s += dw[i*DTR + k] * xp[(size_t)k*DI + j];
    v = f2b(s);
  } else {
    int r = i - DI;
    v = (r < 32) ? f2b(xp[(size_t)(DTR + r)*DI + j]) : (unsigned short)0;
  }
  wb[idx] = v;
}

__global__ __launch_bounds__(256) void k_ln(const float* __restrict__ x,
    const float* __restrict__ add, const float* __restrict__ w, const float* __restrict__ bi,
    float* __restrict__ sumout, float* __restrict__ fout, unsigned short* __restrict__ bout,
    int rows){
  int wv = threadIdx.x >> 6, lane = threadIdx.x & 63;
  int row = blockIdx.x*4 + wv;
  if (row >= rows) return;
  const float* xr = x + (size_t)row*DM;
  float v[12]; float s = 0.f, sq = 0.f;
  #pragma unroll
  for (int i = 0; i < 12; i++){
    int c = lane + 64*i;
    float t = xr[c];
    if (add) t += add[(size_t)row*DM + c];
    if (sumout) sumout[(size_t)row*DM + c] = t;
    v[i] = t; s += t; sq += t*t;
  }
  #pragma unroll
  for (int o = 32; o; o >>= 1){ s += __shfl_xor(s, o, 64); sq += __shfl_xor(sq, o, 64); }
  float mean = s*(1.f/DM);
  float var  = sq*(1.f/DM) - mean*mean;
  float rstd = rsqrtf(var + 1e-5f);
  #pragma unroll
  for (int i = 0; i < 12; i++){
    int c = lane + 64*i;
    float o = (v[i]-mean)*rstd*w[c] + bi[c];
    if (fout) fout[(size_t)row*DM + c] = o;
    if (bout) bout[(size_t)row*DM + c] = f2b(o);
  }
}

__global__ __launch_bounds__(256) void k_lnfin(const float* __restrict__ mlpo,
    const float* __restrict__ resd, const float* __restrict__ w, const float* __restrict__ bi,
    float* __restrict__ h, float* __restrict__ res){
  int wv = threadIdx.x >> 6, lane = threadIdx.x & 63;
  int row = blockIdx.x*4 + wv;
  if (row >= ML) return;
  const float* x0 = mlpo + (size_t)row*DM;
  const float* x1 = mlpo + (size_t)(ML + row)*DM;
  float v0[12], v1[12]; float s0=0,q0=0,s1=0,q1=0;
  #pragma unroll
  for (int i = 0; i < 12; i++){
    int c = lane + 64*i;
    float a = x0[c], b = x1[c];
    v0[i]=a; v1[i]=b; s0+=a; q0+=a*a; s1+=b; q1+=b*b;
  }
  #pragma unroll
  for (int o = 32; o; o >>= 1){
    s0 += __shfl_xor(s0, o, 64); q0 += __shfl_xor(q0, o, 64);
    s1 += __shfl_xor(s1, o, 64); q1 += __shfl_xor(q1, o, 64);
  }
  float m0 = s0*(1.f/DM), m1 = s1*(1.f/DM);
  float r0 = rsqrtf(q0*(1.f/DM) - m0*m0 + 1e-5f);
  float r1 = rsqrtf(q1*(1.f/DM) - m1*m1 + 1e-5f);
  #pragma unroll
  for (int i = 0; i < 12; i++){
    int c = lane + 64*i;
    float o = ((v0[i]-m0)*r0 + (v1[i]-m1)*r1)*w[c] + 2.f*bi[c];
    h[(size_t)row*DM + c] = o;
    res[(size_t)row*DM + c] = resd[(size_t)row*DM + c] + resd[(size_t)(ML+row)*DM + c];
  }
}

// ---- MFMA GEMM core: 128(M) x 64(N) tile, BK=32 ----
static __device__ __forceinline__ void mgemm_core(
    const unsigned short* __restrict__ A, const unsigned short* __restrict__ W, int K,
    unsigned short* As, unsigned short* Bs, f32x4 (&acc)[4][2]){
  int t = threadIdx.x;
  int m0 = blockIdx.y*128, n0 = blockIdx.x*64;
  int lane = t & 63, w = t >> 6;
  int wm = w & 1, wn = w >> 1;
  for (int k0 = 0; k0 < K; k0 += 32){
    #pragma unroll
    for (int si = 0; si < 2; si++){
      int s = t + si*256;
      int row = ((s>>6)<<4) + (s & 15);
      int ko  = ((s>>4) & 3) << 3;
      *(uint4*)&As[s*8] = *(const uint4*)&A[(size_t)(m0+row)*K + k0 + ko];
    }
    {
      int s = t;
      int row = ((s>>6)<<4) + (s & 15);
      int ko  = ((s>>4) & 3) << 3;
      *(uint4*)&Bs[s*8] = *(const uint4*)&W[(size_t)(n0+row)*K + k0 + ko];
    }
    __syncthreads();
    s16x8 af[4], bf[2];
    #pragma unroll
    for (int i = 0; i < 4; i++) af[i] = *(const s16x8*)&As[((wm*4+i)*64 + lane)*8];
    #pragma unroll
    for (int j = 0; j < 2; j++) bf[j] = *(const s16x8*)&Bs[((wn*2+j)*64 + lane)*8];
    #pragma unroll
    for (int i = 0; i < 4; i++)
      #pragma unroll
      for (int j = 0; j < 2; j++)
        acc[i][j] = __builtin_amdgcn_mfma_f32_16x16x32_bf16(af[i], bf[j], acc[i][j], 0, 0, 0);
    __syncthreads();
  }
}

__global__ __launch_bounds__(256) void k_mg0(const unsigned short* __restrict__ A,
    const unsigned short* __restrict__ W, const float* __restrict__ addsrc,
    float* __restrict__ Cf, int N, int K){
  __shared__ __align__(16) unsigned short As[4096], Bs[2048];
  f32x4 acc[4][2] = {};
  mgemm_core(A, W, K, As, Bs, acc);
  int t = threadIdx.x, lane = t & 63, w = t >> 6;
  int wm = w & 1, wn = w >> 1;
  int m0 = blockIdx.y*128, n0 = blockIdx.x*64;
  int cl = lane & 15, qd = lane >> 4;
  #pragma unroll
  for (int i = 0; i < 4; i++){
    int mbase = m0 + (wm*4+i)*16 + qd*4;
    #pragma unroll
    for (int j = 0; j < 2; j++){
      int n = n0 + (wn*2+j)*16 + cl;
      #pragma unroll
      for (int r = 0; r < 4; r++){
        int m = mbase + r;
        float v = acc[i][j][r];
        if (addsrc) v += addsrc[(size_t)(m & (ML-1))*N + n];
        Cf[(size_t)m*N + n] = v;
      }
    }
  }
}

__global__ __launch_bounds__(256) void k_mg1(const unsigned short* __restrict__ A,
    const unsigned short* __restrict__ W, const float* __restrict__ dtb,
    unsigned short* __restrict__ dlb, float* __restrict__ bcout, int K){
  __shared__ __align__(16) unsigned short As[4096], Bs[2048];
  f32x4 acc[4][2] = {};
  mgemm_core(A, W, K, As, Bs, acc);
  int t = threadIdx.x, lane = t & 63, w = t >> 6;
  int wm = w & 1, wn = w >> 1;
  int m0 = blockIdx.y*128, n0 = blockIdx.x*64;
  int cl = lane & 15, qd = lane >> 4;
  #pragma unroll
  for (int i = 0; i < 4; i++){
    int mbase = m0 + (wm*4+i)*16 + qd*4;
    #pragma unroll
    for (int j = 0; j < 2; j++){
      int n = n0 + (wn*2+j)*16 + cl;
      #pragma unroll
      for (int r = 0; r < 4; r++){
        int m = mbase + r;
        float v = acc[i][j][r];
        if (n < DI) dlb[(size_t)m*DI + n] = f2b(softplus_(v + dtb[n]));
        else if (n < DI + 32) bcout[(size_t)m*32 + (n - DI)] = v;
      }
    }
  }
}

__global__ __launch_bounds__(256) void k_mg2(const unsigned short* __restrict__ A,
    const unsigned short* __restrict__ W, unsigned short* __restrict__ Cb, int N, int K){
  __shared__ __align__(16) unsigned short As[4096], Bs[2048];
  f32x4 acc[4][2] = {};
  mgemm_core(A, W, K, As, Bs, acc);
  int t = threadIdx.x, lane = t & 63, w = t >> 6;
  int wm = w & 1, wn = w >> 1;
  int m0 = blockIdx.y*128, n0 = blockIdx.x*64;
  int cl = lane & 15, qd = lane >> 4;
  #pragma unroll
  for (int i = 0; i < 4; i++){
    int mbase = m0 + (wm*4+i)*16 + qd*4;
    #pragma unroll
    for (int j = 0; j < 2; j++){
      int n = n0 + (wn*2+j)*16 + cl;
      #pragma unroll
      for (int r = 0; r < 4; r++){
        int m = mbase + r;
        Cb[(size_t)m*N + n] = f2b(acc[i][j][r]);
      }
    }
  }
}

__global__ void k_conv(const unsigned short* __restrict__ xzb, const float* __restrict__ w,
                       const float* __restrict__ bi, unsigned short* __restrict__ xcb){
  int idx = blockIdx.x*256 + threadIdx.x;   // over 2*ML*DI
  if (idx >= 2*ML*DI) return;
  int d = idx % DI; int r = idx / DI;
  int bl = r % ML; int dir = r / ML;
  int t = bl % LL; int b = bl / LL;
  float acc = bi[d];
  #pragma unroll
  for (int k = 0; k < 4; k++){
    int tp = dir ? (t + 3 - k) : (t - 3 + k);
    if (tp >= 0 && tp < LL)
      acc += w[d*4 + k] * b2f(xzb[((size_t)(b*LL + tp))*(2*DI) + d]);
  }
  xcb[idx] = f2b(silu_(acc));
}

__global__ __launch_bounds__(256) void k_scan1(
    const unsigned short* __restrict__ dlb, const unsigned short* __restrict__ xcb,
    const float* __restrict__ bc, const float* __restrict__ A_log,
    float* __restrict__ sA, float* __restrict__ sH){
  __shared__ float Bsh[CLEN*16];
  int blk = blockIdx.x;
  int dgrp = blk % (DI/256); int rest = blk / (DI/256);
  int ch = rest % NCH; rest /= NCH;
  int b = rest & 1; int dir = rest >> 1;
  int d = dgrp*256 + threadIdx.x;
  int t0 = dir ? (LL-1 - ch*CLEN) : ch*CLEN;
  long step = dir ? -1 : 1;
  long row0 = (long)dir*ML + b*LL + t0;
  #pragma unroll
  for (int rep = 0; rep < CLEN*16/256; rep++){
    int e = threadIdx.x + rep*256;
    int s = e >> 4, n = e & 15;
    Bsh[e] = bc[(size_t)(row0 + s*step)*32 + n];
  }
  __syncthreads();
  float ea[16];
  #pragma unroll
  for (int n = 0; n < 16; n++) ea[n] = -__expf(A_log[d*16 + n]) * 1.44269504f;
  float h[16], P[16];
  #pragma unroll
  for (int n = 0; n < 16; n++){ h[n] = 0.f; P[n] = 1.f; }
  long row = row0;
  for (int s = 0; s < CLEN; s++){
    float de = b2f(dlb[(size_t)row*DI + d]);
    float u  = b2f(xcb[(size_t)row*DI + d]);
    float duu = de*u;
    float Ba[16];
    const f32x4* Bv = (const f32x4*)&Bsh[s*16];
    *(f32x4*)&Ba[0] = Bv[0]; *(f32x4*)&Ba[4] = Bv[1];
    *(f32x4*)&Ba[8] = Bv[2]; *(f32x4*)&Ba[12] = Bv[3];
    #pragma unroll
    for (int n = 0; n < 16; n++){
      float dA = exp2f(de*ea[n]);
      h[n] = dA*h[n] + duu*Ba[n];
      P[n] *= dA;
    }
    row += step;
  }
  size_t sbase = ((((size_t)dir*BB + b)*NCH + ch)*DI + d)*16;
  #pragma unroll
  for (int n = 0; n < 16; n++){ sA[sbase+n] = P[n]; sH[sbase+n] = h[n]; }
}

__global__ __launch_bounds__(256) void k_prefix(
    float* __restrict__ sA, const float* __restrict__ sH){
  int gid = blockIdx.x*256 + threadIdx.x;  // over 2*BB*DI*16
  int dn = gid % (DI*16);
  int db_ = gid / (DI*16);
  float h = 0.f;
  size_t base = (size_t)db_*NCH*DI*16 + dn;
  for (int ch = 0; ch < NCH; ch++){
    size_t idx = base + (size_t)ch*DI*16;
    float a = sA[idx], hh = sH[idx];
    sA[idx] = h;
    h = hh + a*h;
  }
}

__global__ __launch_bounds__(256) void k_scan2(
    const unsigned short* __restrict__ dlb, const unsigned short* __restrict__ xcb,
    const float* __restrict__ bc, const unsigned short* __restrict__ xzb,
    const float* __restrict__ A_log, const float* __restrict__ Dp,
    const float* __restrict__ h0, unsigned short* __restrict__ y){
  __shared__ float BCs[CLEN*32];
  int blk = blockIdx.x;
  int dgrp = blk % (DI/256); int rest = blk / (DI/256);
  int ch = rest % NCH; rest /= NCH;
  int b = rest & 1; int dir = rest >> 1;
  int d = dgrp*256 + threadIdx.x;
  int t0 = dir ? (LL-1 - ch*CLEN) : ch*CLEN;
  long step = dir ? -1 : 1;
  long row0 = (long)dir*ML + b*LL + t0;
  #pragma unroll
  for (int rep = 0; rep < CLEN*32/256; rep++){
    int e = threadIdx.x + rep*256;
    int s = e >> 5, n = e & 31;
    BCs[e] = bc[(size_t)(row0 + s*step)*32 + n];
  }
  __syncthreads();
  float ea[16];
  #pragma unroll
  for (int n = 0; n < 16; n++) ea[n] = -__expf(A_log[d*16 + n]) * 1.44269504f;
  float dD = Dp[d];
  float h[16];
  size_t hbase = ((((size_t)dir*BB + b)*NCH + ch)*DI + d)*16;
  #pragma unroll
  for (int n = 0; n < 16; n++) h[n] = h0[hbase + n];
  long row = row0;
  long zoff = (long)dir*ML;
  for (int s = 0; s < CLEN; s++){
    float de = b2f(dlb[(size_t)row*DI + d]);
    float u  = b2f(xcb[(size_t)row*DI + d]);
    float z  = b2f(xzb[(size_t)(row - zoff)*(2*DI) + DI + d]);
    float duu = de*u;
    float Ba[16], Ca[16];
    const f32x4* Bv = (const f32x4*)&BCs[s*32];
    *(f32x4*)&Ba[0] = Bv[0]; *(f32x4*)&Ba[4] = Bv[1];
    *(f32x4*)&Ba[8] = Bv[2]; *(f32x4*)&Ba[12] = Bv[3];
    *(f32x4*)&Ca[0] = Bv[4]; *(f32x4*)&Ca[4] = Bv[5];
    *(f32x4*)&Ca[8] = Bv[6]; *(f32x4*)&Ca[12] = Bv[7];
    float p0 = 0.f, p1 = 0.f, p2 = 0.f, p3 = 0.f;
    #pragma unroll
    for (int n = 0; n < 16; n += 4){
      float dA0 = exp2f(de*ea[n]),   dA1 = exp2f(de*ea[n+1]);
      float dA2 = exp2f(de*ea[n+2]), dA3 = exp2f(de*ea[n+3]);
      h[n]   = dA0*h[n]   + duu*Ba[n];
      h[n+1] = dA1*h[n+1] + duu*Ba[n+1];
      h[n+2] = dA2*h[n+2] + duu*Ba[n+2];
      h[n+3] = dA3*h[n+3] + duu*Ba[n+3];
      p0 = fmaf(h[n],   Ca[n],   p0);
      p1 = fmaf(h[n+1], Ca[n+1], p1);
      p2 = fmaf(h[n+2], Ca[n+2], p2);
      p3 = fmaf(h[n+3], Ca[n+3], p3);
    }
    float p = (p0+p1) + (p2+p3);
    y[(size_t)row*DI + d] = f2b((p + u*dD) * silu_(z));
    row += step;
  }
}

__global__ void k_gate(const unsigned short* __restrict__ fc1o, unsigned short* __restrict__ g){
  int idx = blockIdx.x*256 + threadIdx.x;   // over 2*ML*DINT
  if (idx >= 2*ML*DINT) return;
  int i = idx % DINT; int bl = idx / DINT;
  float aa = b2f(fc1o[(size_t)bl*2*DINT + i]);
  float gt = b2f(fc1o[(size_t)bl*2*DINT + DINT + i]);
  g[idx] = f2b(aa * silu_(gt));
}

__global__ void k_mean(const float* __restrict__ x, float* __restrict__ out){
  int d = blockIdx.x*256 + threadIdx.x;
  int b = blockIdx.y;
  if (d >= DM) return;
  float s = 0.f;
  for (int t = 0; t < LL; t++) s += x[((size_t)(b*LL + t))*DM + d];
  out[b*DM + d] = s*(1.f/LL);
}

extern "C" void kernel_launch(void* const* d_in, const int* in_sizes, int n_in,
                              void* d_out, int out_size, void* d_ws, size_t ws_size,
                              hipStream_t stream){
  const int*   ids     = (const int*)d_in[0];
  const float* embed   = (const float*)d_in[1];
  const float* norm_w  = (const float*)d_in[2];
  const float* norm_b  = (const float*)d_in[3];
  const float* in_proj = (const float*)d_in[4];
  const float* conv_w  = (const float*)d_in[5];
  const float* conv_b  = (const float*)d_in[6];
  const float* x_proj  = (const float*)d_in[7];
  const float* dt_w    = (const float*)d_in[8];
  const float* dt_b    = (const float*)d_in[9];
  const float* A_log   = (const float*)d_in[10];
  const float* Dp      = (const float*)d_in[11];
  const float* out_pj  = (const float*)d_in[12];
  const float* norm2_w = (const float*)d_in[13];
  const float* norm2_b = (const float*)d_in[14];
  const float* fc1     = (const float*)d_in[15];
  const float* fc2     = (const float*)d_in[16];
  const float* normf_w = (const float*)d_in[17];
  const float* normf_b = (const float*)d_in[18];
  float* out = (float*)d_out;

  const size_t BLD   = (size_t)ML*DM;
  const size_t BLDI  = (size_t)ML*DI;
  const size_t SUMN  = (size_t)2*BB*NCH*DI*16;

  float* f = (float*)d_ws; size_t off = 0;
  float* h     = f+off; off += BLD;
  float* res   = f+off; off += BLD;
  float* rc    = f+off; off += BLD;
  float* resd  = f+off; off += 2*BLD;
  float* bc    = f+off; off += (size_t)2*ML*32;
  float* sA    = f+off; off += SUMN;    // h0 overwrites in place
  float* sH    = f+off; off += SUMN;    // gb aliases after prefix
  unsigned short* gb = (unsigned short*)sH;
  unsigned short* u16 = (unsigned short*)(f + off); size_t uo = 0;
  unsigned short* xlnb = u16+uo; uo += BLD;
  unsigned short* x2b  = u16+uo; uo += 2*BLD;
  unsigned short* xzb  = u16+uo; uo += 2*BLDI;
  unsigned short* xcb  = u16+uo; uo += 2*BLDI;
  unsigned short* dlb  = u16+uo; uo += 2*BLDI;
  unsigned short* wts  = u16+uo;
  const size_t W_IP = (size_t)2*DI*DM, W_OP = (size_t)DM*DI, W_F1 = (size_t)2*DINT*DM,
               W_F2 = (size_t)DM*DINT, W_BG = (size_t)1664*DI;
  const size_t WLAY = W_IP + W_OP + W_F1 + W_F2 + W_BG;
  unsigned short* yb   = xcb;
  unsigned short* fc1o = xcb;            // spans xcb+dlb
  float*          mlpo = (float*)xcb;    // after fc1o dead
  (void)ws_size; (void)in_sizes; (void)n_in; (void)out_size;

  dim3 blk(256);
  auto cdiv = [](int a, int b){ return (a + b - 1)/b; };
  const int scan_blocks = 2*2*NCH*(DI/256);

  // weight prep (both layers, 3 launches, no activation deps)
  Seg8 sg; int cum = 0;
  for (int l = 0; l < 2; l++){
    unsigned short* wl = wts + (size_t)l*WLAY;
    sg.src[l*4+0] = in_proj + (size_t)l*W_IP; sg.dst[l*4+0] = wl;
    sg.src[l*4+1] = out_pj  + (size_t)l*W_OP; sg.dst[l*4+1] = wl + W_IP;
    sg.src[l*4+2] = fc1     + (size_t)l*W_F1; sg.dst[l*4+2] = wl + W_IP + W_OP;
    sg.src[l*4+3] = fc2     + (size_t)l*W_F2; sg.dst[l*4+3] = wl + W_IP + W_OP + W_F1;
  }
  { int sz[8] = {(int)W_IP,(int)W_OP,(int)W_F1,(int)W_F2,(int)W_IP,(int)W_OP,(int)W_F1,(int)W_F2};
    sg.cum[0]=0; for (int i = 0; i < 8; i++){ cum += sz[i]; sg.cum[i+1] = cum; } }
  k_f2bseg<<<cdiv(cum,256), blk, 0, stream>>>(sg);
  for (int l = 0; l < 2; l++)
    k_wbig<<<cdiv(1664*DI,256), blk, 0, stream>>>(dt_w + (size_t)l*DI*DTR,
        x_proj + (size_t)l*(DTR+2*NST)*DI, wts + (size_t)l*WLAY + W_IP + W_OP + W_F1 + W_F2);

  k_embed<<<cdiv(ML*DM,256), blk, 0, stream>>>(ids, embed, h);

  for (int l = 0; l < NLAYER; l++){
    unsigned short* wl   = wts + (size_t)l*WLAY;
    unsigned short* wib  = wl;
    unsigned short* wob  = wl + W_IP;
    unsigned short* wf1b = wl + W_IP + W_OP;
    unsigned short* wf2b = wl + W_IP + W_OP + W_F1;
    unsigned short* wbig = wl + W_IP + W_OP + W_F1 + W_F2;
    const float* nw  = norm_w  + l*DM;
    const float* nb  = norm_b  + l*DM;
    const float* cw  = conv_w  + (size_t)l*DI*4;
    const float* cb  = conv_b  + (size_t)l*DI;
    const float* db  = dt_b    + (size_t)l*DI;
    const float* al  = A_log   + (size_t)l*DI*NST;
    const float* dpl = Dp      + (size_t)l*DI;
    const float* n2w = norm2_w + l*DM;
    const float* n2b = norm2_b + l*DM;

    k_ln<<<ML/4, blk, 0, stream>>>(h, (l==0)?nullptr:res, nw, nb, rc, nullptr, xlnb, ML);
    k_mg2<<<dim3(2*DI/64, ML/128), blk, 0, stream>>>(xlnb, wib, xzb, 2*DI, DM);
    k_conv<<<cdiv(2*ML*DI,256), blk, 0, stream>>>(xzb, cw, cb, xcb);
    k_mg1<<<dim3(1664/64, 2*ML/128), blk, 0, stream>>>(xcb, wbig, db, dlb, bc, DI);
    k_scan1<<<scan_blocks, blk, 0, stream>>>(dlb, xcb, bc, al, sA, sH);
    k_prefix<<<(2*BB*DI*16)/256, blk, 0, stream>>>(sA, sH);
    k_scan2<<<scan_blocks, blk, 0, stream>>>(dlb, xcb, bc, xzb, al, dpl, sA, yb);
    k_mg0<<<dim3(DM/64, 2*ML/128), blk, 0, stream>>>(yb, wob, rc, resd, DM, DI);
    k_ln<<<2*ML/4, blk, 0, stream>>>(resd, nullptr, n2w, n2b, nullptr, nullptr, x2b, 2*ML);
    k_mg2<<<dim3(2*DINT/64, 2*ML/128), blk, 0, stream>>>(x2b, wf1b, fc1o, 2*DINT, DM);
    k_gate<<<cdiv(2*ML*DINT,256), blk, 0, stream>>>(fc1o, gb);
    k_mg0<<<dim3(DM/64, 2*ML/128), blk, 0, stream>>>(gb, wf2b, nullptr, mlpo, DM, DINT);
    k_lnfin<<<ML/4, blk, 0, stream>>>(mlpo, resd, normf_w, normf_b, h, res);
  }

  k_ln<<<ML/4, blk, 0, stream>>>(h, res, normf_w, normf_b, nullptr, rc, nullptr, ML);
  k_mean<<<dim3(3, BB), blk, 0, stream>>>(rc, out);
}